// Round 7
// baseline (260.244 us; speedup 1.0000x reference)
//
#include <hip/hip_runtime.h>

#define NN 100000
#define NE 1000000
#define BSH 8       // bucket shift: 256 cols per bucket
#define BCOLS 256
#define NBUCK 391   // ceil(NN / 256)
#define SBLK 128    // hist/scatter blocks (edge partition)
#define STHR 256
#define CAP 4096    // max edges/bucket on sorted path (mean 2560, std ~51)
#define YSTRIDE 32  // y row: 21 floats + pad -> 128 B aligned

// ---------------------------------------------------------------------------
// K_f: fuse linear chain into Mt[128][24]:
//   Mt[k][0..20] = fused GCN->layer1 column k ([Wu@W1_top; Wm@W1_bot])
//   Mt[k][21]    = b1'[k] = b1[k] + bu@W1_top[:,k] + bm@W1_bot[:,k]
//   Mt[k][22]    = W2[k]
// ---------------------------------------------------------------------------
__global__ __launch_bounds__(128) void fuse_kernel(const float* __restrict__ Wu,
                                                   const float* __restrict__ bu,
                                                   const float* __restrict__ Wm,
                                                   const float* __restrict__ bm,
                                                   const float* __restrict__ W1,
                                                   const float* __restrict__ b1,
                                                   const float* __restrict__ W2,
                                                   float* __restrict__ Mt) {
    const int j = threadIdx.x;
    float w1c[128];
#pragma unroll
    for (int k = 0; k < 128; k++) w1c[k] = W1[k * 128 + j];

    float* row = Mt + j * 24;
#pragma unroll
    for (int m = 0; m < 3; m++) {
        float acc = 0.f;
#pragma unroll
        for (int k = 0; k < 64; k++) acc = fmaf(Wu[m * 64 + k], w1c[k], acc);
        row[m] = acc;
    }
#pragma unroll
    for (int m = 0; m < 18; m++) {
        float acc = 0.f;
#pragma unroll
        for (int k = 0; k < 64; k++) acc = fmaf(Wm[m * 64 + k], w1c[64 + k], acc);
        row[3 + m] = acc;
    }
    float bp = b1[j];
#pragma unroll
    for (int k = 0; k < 64; k++) {
        bp = fmaf(bu[k], w1c[k], bp);
        bp = fmaf(bm[k], w1c[64 + k], bp);
    }
    row[21] = bp;
    row[22] = W2[j];
    row[23] = 0.f;
}

// ---------------------------------------------------------------------------
// K_a: per-(block,bucket) histogram into LDS; H[b*SBLK+blk]. No global atomics.
// ---------------------------------------------------------------------------
__global__ __launch_bounds__(STHR) void bhist_kernel(const int* __restrict__ col,
                                                     int* __restrict__ H) {
    __shared__ int h[NBUCK];
    for (int i = threadIdx.x; i < NBUCK; i += STHR) h[i] = 0;
    __syncthreads();
    for (int e = blockIdx.x * STHR + threadIdx.x; e < NE; e += SBLK * STHR)
        atomicAdd(&h[col[e] >> BSH], 1);
    __syncthreads();
    for (int b = threadIdx.x; b < NBUCK; b += STHR)
        H[b * SBLK + blockIdx.x] = h[b];
}

// ---------------------------------------------------------------------------
// K_b: exclusive scan of H (NBUCK*SBLK = 50048 ints) in one block.
// ---------------------------------------------------------------------------
__global__ __launch_bounds__(1024) void bscan_kernel(int* __restrict__ H) {
    const int TOT = NBUCK * SBLK;          // 50048
    const int PER = 49;                    // 1024*49 >= TOT
    const int t = threadIdx.x;
    const int base = t * PER;
    int v[PER];
    int sum = 0;
#pragma unroll
    for (int i = 0; i < PER; i++) {
        int idx = base + i;
        v[i] = (idx < TOT) ? H[idx] : 0;
        sum += v[i];
    }
    __shared__ int s[1024];
    s[t] = sum;
    __syncthreads();
    for (int off = 1; off < 1024; off <<= 1) {
        int x = (t >= off) ? s[t - off] : 0;
        __syncthreads();
        s[t] += x;
        __syncthreads();
    }
    int run = s[t] - sum;
#pragma unroll
    for (int i = 0; i < PER; i++) {
        int idx = base + i;
        if (idx < TOT) H[idx] = run;
        run += v[i];
    }
}

// ---------------------------------------------------------------------------
// K_c: deterministic scatter into per-(bucket,block) runs. No global atomics.
// Payload: x = (col&255) | (row<<8)  (17+8=25 bits), y = ew bits.
// ---------------------------------------------------------------------------
__global__ __launch_bounds__(STHR) void bscatter_kernel(const int* __restrict__ ei,
                                                        const float* __restrict__ ew,
                                                        const int* __restrict__ H,
                                                        int2* __restrict__ mid) {
    __shared__ int rbase[NBUCK];
    __shared__ int rcnt[NBUCK];
    for (int i = threadIdx.x; i < NBUCK; i += STHR) {
        rbase[i] = H[i * SBLK + blockIdx.x];
        rcnt[i] = 0;
    }
    __syncthreads();
    for (int e = blockIdx.x * STHR + threadIdx.x; e < NE; e += SBLK * STHR) {
        const int c = ei[NE + e];
        const int r = ei[e];
        const float w = ew[e];
        const int b = c >> BSH;
        const int pos = rbase[b] + atomicAdd(&rcnt[b], 1);
        mid[pos] = make_int2((c & (BCOLS - 1)) | (r << BSH), __float_as_int(w));
    }
}

// ---------------------------------------------------------------------------
// K_d: per-bucket degree -> dinv, AND pack the pre-scaled gather table
// y[c][0..20] = dinv[c]*[ux_c, mx_c] into 128-B-aligned 32-float rows.
// ---------------------------------------------------------------------------
__global__ __launch_bounds__(BCOLS) void bdeg_y_kernel(const int2* __restrict__ mid,
                                                       const int* __restrict__ H,
                                                       const float* __restrict__ ux,
                                                       const float* __restrict__ mx,
                                                       float* __restrict__ dinv,
                                                       float* __restrict__ y) {
    __shared__ float dl[BCOLS];
    const int b = blockIdx.x;
    const int t = threadIdx.x;
    dl[t] = 0.f;
    __syncthreads();
    const int start = H[b * SBLK];
    const int end = (b + 1 < NBUCK) ? H[(b + 1) * SBLK] : NE;
    for (int i = start + t; i < end; i += BCOLS) {
        const int2 p = mid[i];
        atomicAdd(&dl[p.x & (BCOLS - 1)], __int_as_float(p.y));
    }
    __syncthreads();
    const int c = b * BCOLS + t;
    if (c < NN) {
        const float dc = rsqrtf(dl[t] + 1.0f);
        dinv[c] = dc;
        float yr[21];
        const float* uc = ux + (size_t)c * 3;
        const float* mc = mx + (size_t)c * 18;
        yr[0] = dc * uc[0];
        yr[1] = dc * uc[1];
        yr[2] = dc * uc[2];
#pragma unroll
        for (int k = 0; k < 18; k++) yr[3 + k] = dc * mc[k];
        float* yo = y + (size_t)c * YSTRIDE;
#pragma unroll
        for (int q = 0; q < 5; q++)
            ((float4*)yo)[q] = make_float4(yr[4 * q], yr[4 * q + 1],
                                           yr[4 * q + 2], yr[4 * q + 3]);
        yo[20] = yr[20];
    }
}

// ---------------------------------------------------------------------------
// K_e: per-bucket counting-sort (indices) + 2-threads-per-col register
// aggregation over the packed y table + fused MLP split across the pair.
// Block = 512 threads; thread t: col cl = t&255, half h = t>>8.
// ---------------------------------------------------------------------------
#define AGT 512
__global__ __launch_bounds__(AGT) void bagg_mlp_kernel(const int2* __restrict__ mid,
                                                       const int* __restrict__ H,
                                                       const float* __restrict__ dinv,
                                                       const float* __restrict__ y,
                                                       const float* __restrict__ Mt,
                                                       const float* __restrict__ b2,
                                                       float* __restrict__ out) {
    __shared__ unsigned short idx16[CAP];     // 8 KB permutation
    __shared__ int cbase[BCOLS + 1];
    __shared__ int ccur[BCOLS];
    __shared__ float xbuf[BCOLS * 21];        // 21 KB partial/final s exchange
    __shared__ float obuf[BCOLS];

    const int b = blockIdx.x;
    const int t = threadIdx.x;
    const int cl = t & (BCOLS - 1);
    const int h = t >> 8;                     // 0 or 1
    const int start = H[b * SBLK];
    const int end = (b + 1 < NBUCK) ? H[(b + 1) * SBLK] : NE;
    const int seg = end - start;
    const int segc = seg < CAP ? seg : CAP;

    // phase 1: per-col counts
    if (t < BCOLS) ccur[t] = 0;
    __syncthreads();
    for (int i = t; i < segc; i += AGT)
        atomicAdd(&ccur[mid[start + i].x & (BCOLS - 1)], 1);
    __syncthreads();

    // phase 2: exclusive scan of 256 counts (threads >=256 ride the syncs)
    int myc = 0;
    if (t < BCOLS) { myc = ccur[t]; cbase[t] = myc; }
    __syncthreads();
    for (int off = 1; off < BCOLS; off <<= 1) {
        int x = 0;
        if (t < BCOLS && t >= off) x = cbase[t - off];
        __syncthreads();
        if (t < BCOLS) cbase[t] += x;
        __syncthreads();
    }
    int incl = (t < BCOLS) ? cbase[t] : 0;
    __syncthreads();
    if (t < BCOLS) {
        cbase[t] = incl - myc;
        ccur[t] = incl - myc;
        if (t == BCOLS - 1) cbase[BCOLS] = incl;
    }
    __syncthreads();

    // phase 3: build permutation
    for (int i = t; i < segc; i += AGT) {
        const int ce = mid[start + i].x & (BCOLS - 1);
        const int pos = atomicAdd(&ccur[ce], 1);
        idx16[pos] = (unsigned short)i;
    }
    __syncthreads();

    // phase 4: 2-thread-per-col register aggregation over packed y
    float s21[21];
#pragma unroll
    for (int m = 0; m < 21; m++) s21[m] = 0.f;

    const int s0 = cbase[cl], s1 = cbase[cl + 1];
    for (int i = s0 + h; i < s1; i += 2) {
        const int2 p = mid[start + idx16[i]];
        const float w = __int_as_float(p.y);
        const float* yr = y + (size_t)(((unsigned)p.x) >> BSH) * YSTRIDE;
        const float4 v0 = ((const float4*)yr)[0];
        const float4 v1 = ((const float4*)yr)[1];
        const float4 v2 = ((const float4*)yr)[2];
        const float4 v3 = ((const float4*)yr)[3];
        const float4 v4 = ((const float4*)yr)[4];
        const float v20 = yr[20];
        s21[0]  = fmaf(w, v0.x, s21[0]);  s21[1]  = fmaf(w, v0.y, s21[1]);
        s21[2]  = fmaf(w, v0.z, s21[2]);  s21[3]  = fmaf(w, v0.w, s21[3]);
        s21[4]  = fmaf(w, v1.x, s21[4]);  s21[5]  = fmaf(w, v1.y, s21[5]);
        s21[6]  = fmaf(w, v1.z, s21[6]);  s21[7]  = fmaf(w, v1.w, s21[7]);
        s21[8]  = fmaf(w, v2.x, s21[8]);  s21[9]  = fmaf(w, v2.y, s21[9]);
        s21[10] = fmaf(w, v2.z, s21[10]); s21[11] = fmaf(w, v2.w, s21[11]);
        s21[12] = fmaf(w, v3.x, s21[12]); s21[13] = fmaf(w, v3.y, s21[13]);
        s21[14] = fmaf(w, v3.z, s21[14]); s21[15] = fmaf(w, v3.w, s21[15]);
        s21[16] = fmaf(w, v4.x, s21[16]); s21[17] = fmaf(w, v4.y, s21[17]);
        s21[18] = fmaf(w, v4.z, s21[18]); s21[19] = fmaf(w, v4.w, s21[19]);
        s21[20] = fmaf(w, v20,  s21[20]);
    }

    // phase 4b: overflow guard (seg > CAP — statistically never; h==0 claims)
    for (int i = CAP; i < seg; i++) {
        const int2 p = mid[start + i];
        if ((p.x & (BCOLS - 1)) == cl && h == 0) {
            const float w = __int_as_float(p.y);
            const float* yr = y + (size_t)(((unsigned)p.x) >> BSH) * YSTRIDE;
#pragma unroll
            for (int m = 0; m < 21; m++) s21[m] = fmaf(w, yr[m], s21[m]);
        }
    }

    const int c = b * BCOLS + cl;

    // phase 5: combine halves; h==0 adds self-loop (y[c]) and scales by dc
    if (h == 1) {
#pragma unroll
        for (int m = 0; m < 21; m++) xbuf[cl * 21 + m] = s21[m];
    }
    __syncthreads();
    if (h == 0 && c < NN) {
        const float dc = dinv[c];
        const float* yc = y + (size_t)c * YSTRIDE;
#pragma unroll
        for (int m = 0; m < 21; m++)
            s21[m] = dc * (s21[m] + xbuf[cl * 21 + m] + yc[m]);
#pragma unroll
        for (int m = 0; m < 21; m++) xbuf[cl * 21 + m] = s21[m];
    }
    __syncthreads();
    if (h == 1) {
#pragma unroll
        for (int m = 0; m < 21; m++) s21[m] = xbuf[cl * 21 + m];
    }

    // phase 6: MLP split — half h computes k in [h*64, h*64+64)
    float o = 0.f;
    const float* mb = Mt + h * 64 * 24;
#pragma unroll 4
    for (int k = 0; k < 64; k++) {
        const float* r = mb + k * 24;
        float hacc = r[21];
#pragma unroll
        for (int m = 0; m < 21; m++) hacc = fmaf(s21[m], r[m], hacc);
        o = fmaf(fmaxf(hacc, 0.f), r[22], o);
    }
    if (h == 1) obuf[cl] = o;
    __syncthreads();
    if (h == 0 && c < NN) out[c] = o + obuf[cl] + b2[0];
}

// ===========================================================================
extern "C" void kernel_launch(void* const* d_in, const int* in_sizes, int n_in,
                              void* d_out, int out_size, void* d_ws, size_t ws_size,
                              hipStream_t stream) {
    const float* ux = (const float*)d_in[0];   // user_x  [N,3]
    const float* mx = (const float*)d_in[1];   // movie_x [N,18]
    const int* ei = (const int*)d_in[2];       // edge_index [2,E]
    const float* ew = (const float*)d_in[3];   // edge_attr [E]
    const float* Wu = (const float*)d_in[4];   // [3,64]
    const float* bu = (const float*)d_in[5];   // [64]
    const float* Wm = (const float*)d_in[6];   // [18,64]
    const float* bm = (const float*)d_in[7];   // [64]
    const float* W1 = (const float*)d_in[8];   // [128,128]
    const float* b1 = (const float*)d_in[9];   // [128]
    const float* W2 = (const float*)d_in[10];  // [128,1]
    const float* b2 = (const float*)d_in[11];  // [1]
    float* out = (float*)d_out;

    char* ws = (char*)d_ws;
    float* dinv = (float*)ws;                        // 400,384 B
    int*   H    = (int*)(ws + 400384);               // 50048*4 = 200,192 B
    float* Mt   = (float*)(ws + 600576);             // 12,288 B
    float* y    = (float*)(ws + 612992);             // 128-B aligned; 12.8 MB
    int2*  mid  = (int2*)(ws + 612992 + (size_t)NBUCK * BCOLS * YSTRIDE * 4);
    // total ~21.4 MB

    fuse_kernel<<<1, 128, 0, stream>>>(Wu, bu, Wm, bm, W1, b1, W2, Mt);
    bhist_kernel<<<SBLK, STHR, 0, stream>>>(ei + NE, H);
    bscan_kernel<<<1, 1024, 0, stream>>>(H);
    bscatter_kernel<<<SBLK, STHR, 0, stream>>>(ei, ew, H, mid);
    bdeg_y_kernel<<<NBUCK, BCOLS, 0, stream>>>(mid, H, ux, mx, dinv, y);
    bagg_mlp_kernel<<<NBUCK, AGT, 0, stream>>>(mid, H, dinv, y, Mt, b2, out);
}